// Round 5
// baseline (231.744 us; speedup 1.0000x reference)
//
#include <hip/hip_runtime.h>
#include <stdint.h>

#define T_SEQ 4096
#define CDIM  1024
#define NH    16
#define DH    64

typedef _Float16 half8 __attribute__((ext_vector_type(8)));
typedef _Float16 half4 __attribute__((ext_vector_type(4)));
typedef float    f32x4 __attribute__((ext_vector_type(4)));

#if __has_builtin(__builtin_amdgcn_exp2f)
#define EXP2F(x) __builtin_amdgcn_exp2f(x)
#else
#define EXP2F(x) exp2f(x)
#endif

#define MFMA_K32(a, b, c) __builtin_amdgcn_mfma_f32_16x16x32_f16(a, b, c, 0, 0, 0)

// pack 2 f32 -> dword of 2 f16 (RTZ): low = a, high = b
__device__ __forceinline__ uint32_t pk2(float a, float b) {
  auto h = __builtin_amdgcn_cvt_pkrtz(a, b);   // __fp16 ext_vector(2)
  return __builtin_bit_cast(uint32_t, h);
}

// async global->LDS, 16B per lane. LDS dest = wave-uniform base + lane*16.
__device__ __forceinline__ void gl_lds16(const void* g, void* l) {
  __builtin_amdgcn_global_load_lds(
      (const __attribute__((address_space(1))) uint32_t*)g,
      (__attribute__((address_space(3))) uint32_t*)l, 16, 0, 0);
}

// ---------------- fp32 -> fp16 convert (weights y=0..3, x y=4..7) ----------------
__global__ void cvt_all_kernel(const float* __restrict__ w0, const float* __restrict__ w1,
                               const float* __restrict__ w2, const float* __restrict__ w3,
                               const float* __restrict__ x,
                               _Float16* __restrict__ o0, _Float16* __restrict__ o1,
                               _Float16* __restrict__ o2, _Float16* __restrict__ o3,
                               _Float16* __restrict__ xo) {
  int y = blockIdx.y;
  const float* src;
  _Float16* dst;
  if (y < 4) {
    src = (y == 0) ? w0 : (y == 1) ? w1 : (y == 2) ? w2 : w3;
    dst = (y == 0) ? o0 : (y == 1) ? o1 : (y == 2) ? o2 : o3;
  } else {
    src = x  + (size_t)(y - 4) * (CDIM * CDIM);
    dst = xo + (size_t)(y - 4) * (CDIM * CDIM);
  }
  int i = (blockIdx.x * blockDim.x + threadIdx.x) * 8;
  float4 f0 = *(const float4*)(src + i);
  float4 f1 = *(const float4*)(src + i + 4);
  half8 h = { (_Float16)f0.x, (_Float16)f0.y, (_Float16)f0.z, (_Float16)f0.w,
              (_Float16)f1.x, (_Float16)f1.y, (_Float16)f1.z, (_Float16)f1.w };
  *(half8*)(dst + i) = h;
}

// ---------------- GEMM core 128x128: C += A[128xK] * B[128xK]^T ----------------
__device__ __forceinline__ void gemm_core(const _Float16* __restrict__ A,
                                          const _Float16* __restrict__ Bm,
                                          _Float16* As, _Float16* Bs,
                                          int bm, int bn,
                                          f32x4 (&acc)[4][4]) {
  const int tid  = threadIdx.x;
  const int lane = tid & 63;
  const int wave = tid >> 6;
  const int waveM = wave >> 1, waveN = wave & 1;
  const int quad = lane >> 4, c16 = lane & 15;

  const int rs0 = wave * 32 + (lane >> 2);
  const int rs1 = rs0 + 16;
  const int dm0 = ((lane & 3) ^ ((rs0 >> 1) & 3)) * 8;
  const int dm1 = ((lane & 3) ^ ((rs1 >> 1) & 3)) * 8;

  const _Float16* gA0 = A  + (size_t)(bm * 128 + rs0) * CDIM + dm0;
  const _Float16* gA1 = A  + (size_t)(bm * 128 + rs1) * CDIM + dm1;
  const _Float16* gB0 = Bm + (size_t)(bn * 128 + rs0) * CDIM + dm0;
  const _Float16* gB1 = Bm + (size_t)(bn * 128 + rs1) * CDIM + dm1;
  _Float16* lA0 = As + wave * 1024;
  _Float16* lA1 = lA0 + 512;
  _Float16* lB0 = Bs + wave * 1024;
  _Float16* lB1 = lB0 + 512;

  const int xsw  = (c16 >> 1) & 3;
  const int offA = (waveM * 64 + c16) * 32 + ((quad ^ xsw) * 8);
  const int offB = (waveN * 64 + c16) * 32 + ((quad ^ xsw) * 8);

  for (int kk = 0; kk < 32; ++kk) {
    gl_lds16(gA0, lA0);
    gl_lds16(gA1, lA1);
    gl_lds16(gB0, lB0);
    gl_lds16(gB1, lB1);
    __syncthreads();
    half8 a[4], b[4];
#pragma unroll
    for (int i = 0; i < 4; ++i) a[i] = *(const half8*)(As + offA + i * 512);
#pragma unroll
    for (int i = 0; i < 4; ++i) b[i] = *(const half8*)(Bs + offB + i * 512);
#pragma unroll
    for (int mi = 0; mi < 4; ++mi)
#pragma unroll
      for (int ni = 0; ni < 4; ++ni)
        acc[mi][ni] = MFMA_K32(a[mi], b[ni], acc[mi][ni]);
    gA0 += 32; gA1 += 32; gB0 += 32; gB1 += 32;
    __syncthreads();
  }
}

// ---------------- GEMM core 64x128: C += A[64xK] * B[128xK]^T ----------------
__device__ __forceinline__ void gemm_core64(const _Float16* __restrict__ A,
                                            const _Float16* __restrict__ Bm,
                                            _Float16* As, _Float16* Bs,
                                            int bm, int bn,
                                            f32x4 (&acc)[2][4]) {
  const int tid  = threadIdx.x;
  const int lane = tid & 63;
  const int wave = tid >> 6;
  const int waveM = wave >> 1, waveN = wave & 1;
  const int quad = lane >> 4, c16 = lane & 15;

  const int rsA = wave * 16 + (lane >> 2);
  const int dmA = ((lane & 3) ^ ((rsA >> 1) & 3)) * 8;
  const int rs0 = wave * 32 + (lane >> 2);
  const int rs1 = rs0 + 16;
  const int dm0 = ((lane & 3) ^ ((rs0 >> 1) & 3)) * 8;
  const int dm1 = ((lane & 3) ^ ((rs1 >> 1) & 3)) * 8;

  const _Float16* gA0 = A  + (size_t)(bm * 64  + rsA) * CDIM + dmA;
  const _Float16* gB0 = Bm + (size_t)(bn * 128 + rs0) * CDIM + dm0;
  const _Float16* gB1 = Bm + (size_t)(bn * 128 + rs1) * CDIM + dm1;
  _Float16* lA0 = As + wave * 512;
  _Float16* lB0 = Bs + wave * 1024;
  _Float16* lB1 = lB0 + 512;

  const int xsw  = (c16 >> 1) & 3;
  const int offA = (waveM * 32 + c16) * 32 + ((quad ^ xsw) * 8);
  const int offB = (waveN * 64 + c16) * 32 + ((quad ^ xsw) * 8);

  for (int kk = 0; kk < 32; ++kk) {
    gl_lds16(gA0, lA0);
    gl_lds16(gB0, lB0);
    gl_lds16(gB1, lB1);
    __syncthreads();
    half8 a[2], b[4];
#pragma unroll
    for (int i = 0; i < 2; ++i) a[i] = *(const half8*)(As + offA + i * 512);
#pragma unroll
    for (int i = 0; i < 4; ++i) b[i] = *(const half8*)(Bs + offB + i * 512);
#pragma unroll
    for (int mi = 0; mi < 2; ++mi)
#pragma unroll
      for (int ni = 0; ni < 4; ++ni)
        acc[mi][ni] = MFMA_K32(a[mi], b[ni], acc[mi][ni]);
    gA0 += 32; gB0 += 32; gB1 += 32;
    __syncthreads();
  }
}

// ---------------- fused QKV projection ----------------
// z=0: q -> qh [H][T][D] scaled by (1/8)*log2(e).
// z=1: k -> kh in MFMA A-FRAGMENT order: kh[h][kt][c*4+kb][lane][j] =
//      K[h][kt*64 + kb*16 + (lane&15)][c*32 + (lane>>4)*8 + j]
// z=2: v -> vth in A-FRAGMENT order of V^T: vth[h][kt][kb32*4+db][lane][j] =
//      V^T[h][db*16 + (lane&15)][kt*64 + kb32*32 + (lane>>4)*8 + j]
// attn then loads every fragment as one coalesced global dwordx4 (lane*16B).
__global__ __launch_bounds__(256) void qkv_gemm(
    const _Float16* __restrict__ xh,
    const _Float16* __restrict__ wqh, const _Float16* __restrict__ wkh, const _Float16* __restrict__ wvh,
    const float* __restrict__ bq, const float* __restrict__ bk, const float* __restrict__ bv,
    _Float16* __restrict__ qh, _Float16* __restrict__ kh, _Float16* __restrict__ vth) {
  __shared__ __align__(16) _Float16 As[128 * 32];
  __shared__ __align__(16) _Float16 Bs[128 * 32];
  const int z = blockIdx.z;
  const _Float16* W   = (z == 0) ? wqh : ((z == 1) ? wkh : wvh);
  const float*    bias = (z == 0) ? bq  : ((z == 1) ? bk  : bv);

  f32x4 acc[4][4];
  const f32x4 zf = {0.f, 0.f, 0.f, 0.f};
#pragma unroll
  for (int i = 0; i < 4; ++i)
#pragma unroll
    for (int j = 0; j < 4; ++j) acc[i][j] = zf;

  gemm_core(xh, W, As, Bs, blockIdx.x, blockIdx.y, acc);

  const int lane = threadIdx.x & 63, wave = threadIdx.x >> 6;
  const int waveM = wave >> 1, waveN = wave & 1;
  const int quad = lane >> 4, c16 = lane & 15;
  const int rowb = blockIdx.x * 128 + waveM * 64;
  const int colb = blockIdx.y * 128 + waveN * 64;

  float bsv[4];
#pragma unroll
  for (int ni = 0; ni < 4; ++ni) bsv[ni] = bias[colb + ni * 16 + c16];

  if (z == 0) {
    const float scl = 0.18033688011112042f;  // (1/8)*log2(e) folded into q
#pragma unroll
    for (int mi = 0; mi < 4; ++mi)
#pragma unroll
      for (int ni = 0; ni < 4; ++ni) {
        int col = colb + ni * 16 + c16;
        int hh = col >> 6, dd = col & 63;
#pragma unroll
        for (int r = 0; r < 4; ++r) {
          int row = rowb + mi * 16 + quad * 4 + r;
          qh[(size_t)(hh * T_SEQ + row) * DH + dd] = (_Float16)((acc[mi][ni][r] + bsv[ni]) * scl);
        }
      }
  } else if (z == 1) {
    // K fragment layout (2B scattered stores, same granularity as before)
#pragma unroll
    for (int mi = 0; mi < 4; ++mi)
#pragma unroll
      for (int ni = 0; ni < 4; ++ni) {
        int col = colb + ni * 16 + c16;
        int hh = col >> 6, dd = col & 63;
        int cc = dd >> 5, qf_ = (dd >> 3) & 3, j = dd & 7;
#pragma unroll
        for (int r = 0; r < 4; ++r) {
          int t = rowb + mi * 16 + quad * 4 + r;
          int kt = t >> 6, k64 = t & 63;
          int kb = k64 >> 4, c16f = k64 & 15;
          size_t off = ((size_t)(hh * 64 + kt)) * 4096 +
                       (size_t)(((cc * 4 + kb) * 64) + qf_ * 16 + c16f) * 8 + j;
          kh[off] = (_Float16)(acc[mi][ni][r] + bsv[ni]);
        }
      }
  } else {
    // V^T fragment layout (8B stores, same granularity as before)
#pragma unroll
    for (int mi = 0; mi < 4; ++mi)
#pragma unroll
      for (int ni = 0; ni < 4; ++ni) {
        int col = colb + ni * 16 + c16;
        int hh = col >> 6, d = col & 63;
        int db = (d >> 4) & 3, c16f = d & 15;
        int t0 = rowb + mi * 16 + quad * 4;
        int kt = t0 >> 6, key = t0 & 63;
        int kb32 = key >> 5, qf_ = (key >> 3) & 3, j0 = key & 7;
        half4 h4;
#pragma unroll
        for (int r = 0; r < 4; ++r) h4[r] = (_Float16)(acc[mi][ni][r] + bsv[ni]);
        size_t off = ((size_t)(hh * 64 + kt)) * 4096 +
                     (size_t)((kb32 * 4 + db) * 64 + qf_ * 16 + c16f) * 8 + j0;
        *(half4*)(vth + off) = h4;
      }
  }
}

// ---------------- output projection: out = ctx @ Wo^T + bo (fp32), 64x128 tiles ----------------
__global__ __launch_bounds__(256) void out_gemm(
    const _Float16* __restrict__ ctx, const _Float16* __restrict__ woh,
    const float* __restrict__ bo, float* __restrict__ out) {
  __shared__ __align__(16) _Float16 As[64 * 32];
  __shared__ __align__(16) _Float16 Bs[128 * 32];
  f32x4 acc[2][4];
  const f32x4 zf = {0.f, 0.f, 0.f, 0.f};
#pragma unroll
  for (int i = 0; i < 2; ++i)
#pragma unroll
    for (int j = 0; j < 4; ++j) acc[i][j] = zf;

  gemm_core64(ctx, woh, As, Bs, blockIdx.x, blockIdx.y, acc);

  const int lane = threadIdx.x & 63, wave = threadIdx.x >> 6;
  const int waveM = wave >> 1, waveN = wave & 1;
  const int quad = lane >> 4, c16 = lane & 15;
  const int rowb = blockIdx.x * 64 + waveM * 32;
  const int colb = blockIdx.y * 128 + waveN * 64;

  float bsv[4];
#pragma unroll
  for (int ni = 0; ni < 4; ++ni) bsv[ni] = bo[colb + ni * 16 + c16];

#pragma unroll
  for (int mi = 0; mi < 2; ++mi)
#pragma unroll
    for (int ni = 0; ni < 4; ++ni) {
      int col = colb + ni * 16 + c16;
#pragma unroll
      for (int r = 0; r < 4; ++r) {
        int row = rowb + mi * 16 + quad * 4 + r;
        out[(size_t)row * CDIM + col] = acc[mi][ni][r] + bsv[ni];
      }
    }
}

// ---------------- flash attention (R8: barrier-free, frag-layout global loads) ----------------
// R7b post-mortem: P->register path was a WIN (93->81us, conflicts 4.3M->98K)
// but both pipes still <=46%: the residual coupling is K/V LDS staging
// (__syncthreads convoys + ds_read lgkm chains). R8: qkv_gemm emits K/V^T
// pre-swizzled in MFMA fragment order, so every A-frag is ONE coalesced
// global_load_dwordx4 (lane*16B) from L2 (K+V = 1MB/head, L2-resident).
// No LDS staging, no barriers; waves fully independent. K/V double-buffered
// in registers; loads for tile t+1 issue a full tile (~2000cy) before use.
__global__ __launch_bounds__(256, 2) void attn_kernel(
    const _Float16* __restrict__ qh, const _Float16* __restrict__ kfb,
    const _Float16* __restrict__ vfb, _Float16* __restrict__ ctx) {
  __shared__ __align__(16) _Float16 Ps[4][32 * 64];   // 16 KB, epilogue only

  const int tid = threadIdx.x, lane = tid & 63, wave = tid >> 6;
  const int quad = lane >> 4, c16 = lane & 15;
  const int h = blockIdx.y;
  const int qw = blockIdx.x * 128 + wave * 32;

  // Q fragments (B-operand of 16x16x32)
  half8 qf[2][2];
#pragma unroll
  for (int qg = 0; qg < 2; ++qg)
#pragma unroll
    for (int c = 0; c < 2; ++c)
      qf[qg][c] = *(const half8*)(qh + (size_t)(h * T_SEQ + qw + qg * 16 + c16) * DH + c * 32 + quad * 8);

  // per-head fragment bases; each lane reads its 16B slot
  const _Float16* pK = kfb + (size_t)h * 64 * 4096 + lane * 8;
  const _Float16* pV = vfb + (size_t)h * 64 * 4096 + lane * 8;

  f32x4 o[2][4];
  f32x4 lacc[2];
  const f32x4 zf = {0.f, 0.f, 0.f, 0.f};
#pragma unroll
  for (int qg = 0; qg < 2; ++qg) {
#pragma unroll
    for (int db = 0; db < 4; ++db) o[qg][db] = zf;
    lacc[qg] = zf;
  }
  const half8 ones8 = { (_Float16)1, (_Float16)1, (_Float16)1, (_Float16)1,
                        (_Float16)1, (_Float16)1, (_Float16)1, (_Float16)1 };

  union U8 { uint32_t u[4]; half8 h; };

  auto LD = [&](half8 (&dst)[8], const _Float16* base, int kt) {
#pragma unroll
    for (int f = 0; f < 8; ++f)
      dst[f] = *(const half8*)(base + (size_t)kt * 4096 + f * 512);
  };

  auto compute = [&](const half8 (&kf)[8], const half8 (&vf)[8]) {
    // S^T - 16: s[qg][kb][r] = score[key=kb*16+quad*4+r][qcol=qg*16+c16] - 16
    const f32x4 minit = {-16.f, -16.f, -16.f, -16.f};
    f32x4 s[2][4];
#pragma unroll
    for (int qg = 0; qg < 2; ++qg)
#pragma unroll
      for (int kb = 0; kb < 4; ++kb) s[qg][kb] = minit;
    __builtin_amdgcn_s_setprio(1);
#pragma unroll
    for (int c = 0; c < 2; ++c)
#pragma unroll
      for (int kb = 0; kb < 4; ++kb) {
        s[0][kb] = MFMA_K32(kf[c * 4 + kb], qf[0][c], s[0][kb]);
        s[1][kb] = MFMA_K32(kf[c * 4 + kb], qf[1][c], s[1][kb]);
      }
    __builtin_amdgcn_s_setprio(0);

    // p = exp2(s); build PV B-frags in registers (cvt_pkrtz + permlane swaps)
    half8 bp[2][2];   // [qg][kb32]
#pragma unroll
    for (int qg = 0; qg < 2; ++qg) {
      float p[4][4];
#pragma unroll
      for (int kb = 0; kb < 4; ++kb)
#pragma unroll
        for (int r = 0; r < 4; ++r) p[kb][r] = EXP2F(s[qg][kb][r]);
#pragma unroll
      for (int kb32 = 0; kb32 < 2; ++kb32) {
        uint32_t a0 = pk2(p[2 * kb32][0],     p[2 * kb32][1]);
        uint32_t a1 = pk2(p[2 * kb32][2],     p[2 * kb32][3]);
        uint32_t b0 = pk2(p[2 * kb32 + 1][0], p[2 * kb32 + 1][1]);
        uint32_t b1 = pk2(p[2 * kb32 + 1][2], p[2 * kb32 + 1][3]);
        asm("v_permlane32_swap_b32 %0, %1" : "+v"(a0), "+v"(b0));
        asm("v_permlane16_swap_b32 %0, %1" : "+v"(a0), "+v"(b0));
        asm("v_permlane32_swap_b32 %0, %1" : "+v"(a1), "+v"(b1));
        asm("v_permlane16_swap_b32 %0, %1" : "+v"(a1), "+v"(b1));
        U8 u;
        u.u[0] = a0; u.u[1] = a1; u.u[2] = b0; u.u[3] = b1;
        bp[qg][kb32] = u.h;
      }
    }

    // PV + l MFMA from register V-frags
    __builtin_amdgcn_s_setprio(1);
#pragma unroll
    for (int kb32 = 0; kb32 < 2; ++kb32)
#pragma unroll
      for (int qg = 0; qg < 2; ++qg) {
        lacc[qg] = MFMA_K32(ones8, bp[qg][kb32], lacc[qg]);
#pragma unroll
        for (int db = 0; db < 4; ++db)
          o[qg][db] = MFMA_K32(vf[kb32 * 4 + db], bp[qg][kb32], o[qg][db]);
      }
    __builtin_amdgcn_s_setprio(0);
  };

  // register double-buffered tile pipeline, no barriers
  half8 k0[8], v0[8], k1[8], v1[8];
  LD(k0, pK, 0); LD(v0, pV, 0);
  for (int it = 0; it < 32; ++it) {
    const int t = 2 * it;
    LD(k1, pK, t + 1); LD(v1, pV, t + 1);
    compute(k0, v0);
    if (it < 31) { LD(k0, pK, t + 2); LD(v0, pV, t + 2); }
    compute(k1, v1);
  }

  // epilogue: O/l -> wave-private LDS as [q][d] (XOR swizzle) -> coalesced stores
  _Float16* Pw = &Ps[wave][0];
#pragma unroll
  for (int qg = 0; qg < 2; ++qg) {
    float inv = 1.f / lacc[qg][0];   // every reg of lacc holds l[q=c16]
#pragma unroll
    for (int db = 0; db < 4; ++db) {
      half4 h4;
#pragma unroll
      for (int r = 0; r < 4; ++r) h4[r] = (_Float16)(o[qg][db][r] * inv);
      int row = qg * 16 + c16;
      int g   = db * 2 + (quad >> 1);
      *(half4*)(Pw + row * 64 + ((g ^ (row & 7)) * 8) + (quad & 1) * 4) = h4;
    }
  }
  const int q = lane >> 1, hv = lane & 1;
#pragma unroll
  for (int i = 0; i < 4; ++i) {
    int g = hv * 4 + i;
    half8 vv = *(const half8*)(Pw + q * 64 + ((g ^ (q & 7)) * 8));
    *(half8*)(ctx + (size_t)(qw + q) * CDIM + h * DH + g * 8) = vv;
  }
}

// ---------------- launch ----------------
extern "C" void kernel_launch(void* const* d_in, const int* in_sizes, int n_in,
                              void* d_out, int out_size, void* d_ws, size_t ws_size,
                              hipStream_t stream) {
  const float* x  = (const float*)d_in[0];
  const float* Wq = (const float*)d_in[1];
  const float* bq = (const float*)d_in[2];
  const float* Wk = (const float*)d_in[3];
  const float* bk = (const float*)d_in[4];
  const float* Wv = (const float*)d_in[5];
  const float* bv = (const float*)d_in[6];
  const float* Wo = (const float*)d_in[7];
  const float* bo = (const float*)d_in[8];
  float* out = (float*)d_out;

  char* ws = (char*)d_ws;
  _Float16* xh  = (_Float16*)(ws);                    // 8 MB; reused as ctx after QKV
  _Float16* qh  = (_Float16*)(ws + ((size_t)8  << 20));
  _Float16* kh  = (_Float16*)(ws + ((size_t)16 << 20));   // 8 MB K frag layout
  _Float16* vth = (_Float16*)(ws + ((size_t)24 << 20));   // 8 MB V^T frag layout
  _Float16* wqh = (_Float16*)(ws + ((size_t)32 << 20));
  _Float16* wkh = (_Float16*)(ws + ((size_t)34 << 20));
  _Float16* wvh = (_Float16*)(ws + ((size_t)36 << 20));
  _Float16* woh = (_Float16*)(ws + ((size_t)38 << 20));
  _Float16* ctx = xh;  // xh dead after QKV GEMMs

  cvt_all_kernel<<<dim3(512, 8), 256, 0, stream>>>(Wq, Wk, Wv, Wo, x,
                                                   wqh, wkh, wvh, woh, xh);
  qkv_gemm<<<dim3(32, 8, 3), 256, 0, stream>>>(xh, wqh, wkh, wvh, bq, bk, bv, qh, kh, vth);
  attn_kernel<<<dim3(32, 16), 256, 0, stream>>>(qh, kh, vth, ctx);
  out_gemm<<<dim3(64, 8), 256, 0, stream>>>(ctx, woh, bo, out);
}

// Round 6
// 221.761 us; speedup vs baseline: 1.0450x; 1.0450x over previous
//
#include <hip/hip_runtime.h>
#include <stdint.h>

#define T_SEQ 4096
#define CDIM  1024
#define NH    16
#define DH    64

typedef _Float16 half8 __attribute__((ext_vector_type(8)));
typedef _Float16 half4 __attribute__((ext_vector_type(4)));
typedef float    f32x4 __attribute__((ext_vector_type(4)));

#if __has_builtin(__builtin_amdgcn_exp2f)
#define EXP2F(x) __builtin_amdgcn_exp2f(x)
#else
#define EXP2F(x) exp2f(x)
#endif

#define MFMA_K32(a, b, c) __builtin_amdgcn_mfma_f32_16x16x32_f16(a, b, c, 0, 0, 0)

// pack 2 f32 -> dword of 2 f16 (RTZ): low = a, high = b
__device__ __forceinline__ uint32_t pk2(float a, float b) {
  auto h = __builtin_amdgcn_cvt_pkrtz(a, b);   // __fp16 ext_vector(2)
  return __builtin_bit_cast(uint32_t, h);
}

// async global->LDS, 16B per lane. LDS dest = wave-uniform base + lane*16.
__device__ __forceinline__ void gl_lds16(const void* g, void* l) {
  __builtin_amdgcn_global_load_lds(
      (const __attribute__((address_space(1))) uint32_t*)g,
      (__attribute__((address_space(3))) uint32_t*)l, 16, 0, 0);
}

// ---------------- fp32 -> fp16 convert (weights y=0..3, x y=4..7) ----------------
__global__ void cvt_all_kernel(const float* __restrict__ w0, const float* __restrict__ w1,
                               const float* __restrict__ w2, const float* __restrict__ w3,
                               const float* __restrict__ x,
                               _Float16* __restrict__ o0, _Float16* __restrict__ o1,
                               _Float16* __restrict__ o2, _Float16* __restrict__ o3,
                               _Float16* __restrict__ xo) {
  int y = blockIdx.y;
  const float* src;
  _Float16* dst;
  if (y < 4) {
    src = (y == 0) ? w0 : (y == 1) ? w1 : (y == 2) ? w2 : w3;
    dst = (y == 0) ? o0 : (y == 1) ? o1 : (y == 2) ? o2 : o3;
  } else {
    src = x  + (size_t)(y - 4) * (CDIM * CDIM);
    dst = xo + (size_t)(y - 4) * (CDIM * CDIM);
  }
  int i = (blockIdx.x * blockDim.x + threadIdx.x) * 8;
  float4 f0 = *(const float4*)(src + i);
  float4 f1 = *(const float4*)(src + i + 4);
  half8 h = { (_Float16)f0.x, (_Float16)f0.y, (_Float16)f0.z, (_Float16)f0.w,
              (_Float16)f1.x, (_Float16)f1.y, (_Float16)f1.z, (_Float16)f1.w };
  *(half8*)(dst + i) = h;
}

// ---------------- GEMM core 128x128: C += A[128xK] * B[128xK]^T ----------------
__device__ __forceinline__ void gemm_core(const _Float16* __restrict__ A,
                                          const _Float16* __restrict__ Bm,
                                          _Float16* As, _Float16* Bs,
                                          int bm, int bn,
                                          f32x4 (&acc)[4][4]) {
  const int tid  = threadIdx.x;
  const int lane = tid & 63;
  const int wave = tid >> 6;
  const int waveM = wave >> 1, waveN = wave & 1;
  const int quad = lane >> 4, c16 = lane & 15;

  const int rs0 = wave * 32 + (lane >> 2);
  const int rs1 = rs0 + 16;
  const int dm0 = ((lane & 3) ^ ((rs0 >> 1) & 3)) * 8;
  const int dm1 = ((lane & 3) ^ ((rs1 >> 1) & 3)) * 8;

  const _Float16* gA0 = A  + (size_t)(bm * 128 + rs0) * CDIM + dm0;
  const _Float16* gA1 = A  + (size_t)(bm * 128 + rs1) * CDIM + dm1;
  const _Float16* gB0 = Bm + (size_t)(bn * 128 + rs0) * CDIM + dm0;
  const _Float16* gB1 = Bm + (size_t)(bn * 128 + rs1) * CDIM + dm1;
  _Float16* lA0 = As + wave * 1024;
  _Float16* lA1 = lA0 + 512;
  _Float16* lB0 = Bs + wave * 1024;
  _Float16* lB1 = lB0 + 512;

  const int xsw  = (c16 >> 1) & 3;
  const int offA = (waveM * 64 + c16) * 32 + ((quad ^ xsw) * 8);
  const int offB = (waveN * 64 + c16) * 32 + ((quad ^ xsw) * 8);

  for (int kk = 0; kk < 32; ++kk) {
    gl_lds16(gA0, lA0);
    gl_lds16(gA1, lA1);
    gl_lds16(gB0, lB0);
    gl_lds16(gB1, lB1);
    __syncthreads();
    half8 a[4], b[4];
#pragma unroll
    for (int i = 0; i < 4; ++i) a[i] = *(const half8*)(As + offA + i * 512);
#pragma unroll
    for (int i = 0; i < 4; ++i) b[i] = *(const half8*)(Bs + offB + i * 512);
#pragma unroll
    for (int mi = 0; mi < 4; ++mi)
#pragma unroll
      for (int ni = 0; ni < 4; ++ni)
        acc[mi][ni] = MFMA_K32(a[mi], b[ni], acc[mi][ni]);
    gA0 += 32; gA1 += 32; gB0 += 32; gB1 += 32;
    __syncthreads();
  }
}

// ---------------- GEMM core 64x128: C += A[64xK] * B[128xK]^T ----------------
__device__ __forceinline__ void gemm_core64(const _Float16* __restrict__ A,
                                            const _Float16* __restrict__ Bm,
                                            _Float16* As, _Float16* Bs,
                                            int bm, int bn,
                                            f32x4 (&acc)[2][4]) {
  const int tid  = threadIdx.x;
  const int lane = tid & 63;
  const int wave = tid >> 6;
  const int waveM = wave >> 1, waveN = wave & 1;
  const int quad = lane >> 4, c16 = lane & 15;

  const int rsA = wave * 16 + (lane >> 2);
  const int dmA = ((lane & 3) ^ ((rsA >> 1) & 3)) * 8;
  const int rs0 = wave * 32 + (lane >> 2);
  const int rs1 = rs0 + 16;
  const int dm0 = ((lane & 3) ^ ((rs0 >> 1) & 3)) * 8;
  const int dm1 = ((lane & 3) ^ ((rs1 >> 1) & 3)) * 8;

  const _Float16* gA0 = A  + (size_t)(bm * 64  + rsA) * CDIM + dmA;
  const _Float16* gB0 = Bm + (size_t)(bn * 128 + rs0) * CDIM + dm0;
  const _Float16* gB1 = Bm + (size_t)(bn * 128 + rs1) * CDIM + dm1;
  _Float16* lA0 = As + wave * 512;
  _Float16* lB0 = Bs + wave * 1024;
  _Float16* lB1 = lB0 + 512;

  const int xsw  = (c16 >> 1) & 3;
  const int offA = (waveM * 32 + c16) * 32 + ((quad ^ xsw) * 8);
  const int offB = (waveN * 64 + c16) * 32 + ((quad ^ xsw) * 8);

  for (int kk = 0; kk < 32; ++kk) {
    gl_lds16(gA0, lA0);
    gl_lds16(gB0, lB0);
    gl_lds16(gB1, lB1);
    __syncthreads();
    half8 a[2], b[4];
#pragma unroll
    for (int i = 0; i < 2; ++i) a[i] = *(const half8*)(As + offA + i * 512);
#pragma unroll
    for (int i = 0; i < 4; ++i) b[i] = *(const half8*)(Bs + offB + i * 512);
#pragma unroll
    for (int mi = 0; mi < 2; ++mi)
#pragma unroll
      for (int ni = 0; ni < 4; ++ni)
        acc[mi][ni] = MFMA_K32(a[mi], b[ni], acc[mi][ni]);
    gA0 += 32; gB0 += 32; gB1 += 32;
    __syncthreads();
  }
}

// ---------------- fused QKV projection ----------------
// z=0: q -> qh [H][T][D] scaled by (1/8)*log2(e); z=1: k -> kh [H][T][D];
// z=2: v -> vth [H][D][T] (V^T; attn stages it to LDS and reads half8 A-frags).
__global__ __launch_bounds__(256) void qkv_gemm(
    const _Float16* __restrict__ xh,
    const _Float16* __restrict__ wqh, const _Float16* __restrict__ wkh, const _Float16* __restrict__ wvh,
    const float* __restrict__ bq, const float* __restrict__ bk, const float* __restrict__ bv,
    _Float16* __restrict__ qh, _Float16* __restrict__ kh, _Float16* __restrict__ vth) {
  __shared__ __align__(16) _Float16 As[128 * 32];
  __shared__ __align__(16) _Float16 Bs[128 * 32];
  const int z = blockIdx.z;
  const _Float16* W   = (z == 0) ? wqh : ((z == 1) ? wkh : wvh);
  const float*    bias = (z == 0) ? bq  : ((z == 1) ? bk  : bv);

  f32x4 acc[4][4];
  const f32x4 zf = {0.f, 0.f, 0.f, 0.f};
#pragma unroll
  for (int i = 0; i < 4; ++i)
#pragma unroll
    for (int j = 0; j < 4; ++j) acc[i][j] = zf;

  gemm_core(xh, W, As, Bs, blockIdx.x, blockIdx.y, acc);

  const int lane = threadIdx.x & 63, wave = threadIdx.x >> 6;
  const int waveM = wave >> 1, waveN = wave & 1;
  const int quad = lane >> 4, c16 = lane & 15;
  const int rowb = blockIdx.x * 128 + waveM * 64;
  const int colb = blockIdx.y * 128 + waveN * 64;

  float bsv[4];
#pragma unroll
  for (int ni = 0; ni < 4; ++ni) bsv[ni] = bias[colb + ni * 16 + c16];

  if (z < 2) {
    _Float16* outp = (z == 0) ? qh : kh;
    const float scl = (z == 0) ? 0.18033688011112042f : 1.0f;  // (1/8)*log2(e) folded into q
#pragma unroll
    for (int mi = 0; mi < 4; ++mi)
#pragma unroll
      for (int ni = 0; ni < 4; ++ni) {
        int col = colb + ni * 16 + c16;
        int hh = col >> 6, dd = col & 63;
#pragma unroll
        for (int r = 0; r < 4; ++r) {
          int row = rowb + mi * 16 + quad * 4 + r;
          outp[(size_t)(hh * T_SEQ + row) * DH + dd] = (_Float16)((acc[mi][ni][r] + bsv[ni]) * scl);
        }
      }
  } else {
#pragma unroll
    for (int mi = 0; mi < 4; ++mi)
#pragma unroll
      for (int ni = 0; ni < 4; ++ni) {
        int col  = colb + ni * 16 + c16;
        int row0 = rowb + mi * 16 + quad * 4;
        half4 h4;
#pragma unroll
        for (int r = 0; r < 4; ++r) h4[r] = (_Float16)(acc[mi][ni][r] + bsv[ni]);
        *(half4*)(vth + (size_t)col * T_SEQ + row0) = h4;   // [H][D][T]
      }
  }
}

// ---------------- output projection: out = ctx @ Wo^T + bo (fp32), 64x128 tiles ----------------
__global__ __launch_bounds__(256) void out_gemm(
    const _Float16* __restrict__ ctx, const _Float16* __restrict__ woh,
    const float* __restrict__ bo, float* __restrict__ out) {
  __shared__ __align__(16) _Float16 As[64 * 32];
  __shared__ __align__(16) _Float16 Bs[128 * 32];
  f32x4 acc[2][4];
  const f32x4 zf = {0.f, 0.f, 0.f, 0.f};
#pragma unroll
  for (int i = 0; i < 2; ++i)
#pragma unroll
    for (int j = 0; j < 4; ++j) acc[i][j] = zf;

  gemm_core64(ctx, woh, As, Bs, blockIdx.x, blockIdx.y, acc);

  const int lane = threadIdx.x & 63, wave = threadIdx.x >> 6;
  const int waveM = wave >> 1, waveN = wave & 1;
  const int quad = lane >> 4, c16 = lane & 15;
  const int rowb = blockIdx.x * 64 + waveM * 32;
  const int colb = blockIdx.y * 128 + waveN * 64;

  float bsv[4];
#pragma unroll
  for (int ni = 0; ni < 4; ++ni) bsv[ni] = bo[colb + ni * 16 + c16];

#pragma unroll
  for (int mi = 0; mi < 2; ++mi)
#pragma unroll
    for (int ni = 0; ni < 4; ++ni) {
      int col = colb + ni * 16 + c16;
#pragma unroll
      for (int r = 0; r < 4; ++r) {
        int row = rowb + mi * 16 + quad * 4 + r;
        out[(size_t)row * CDIM + col] = acc[mi][ni][r] + bsv[ni];
      }
    }
}

// ---------------- flash attention (R9: split-K wave groups, 8 waves/block) ----------------
// R8 post-mortem: global-direct frag loads = 4x L2 traffic -> regression;
// reverted to R7b's LDS staging + in-register P (proven 81us). R9 adds TLP
// without redundancy: 512-thread blocks, 2 wave-GROUPS of 4 waves. Group g
// processes keys [g*2048, g*2048+2048) for the SAME 128 q-rows with its own
// K/V double-buffer. Per-wave work halves, waves/SIMD double (2->4), total
// staging/LDS/exp2 traffic UNCHANGED. Fixed-bias softmax => partials add:
// o=o0+o1, l=l0+l1, combined once via LDS at the end. LDS 64KB -> 2 blk/CU
// = 16 waves/CU. launch_bounds(512,4) caps VGPR<=128 so all waves resident.
__global__ __launch_bounds__(512, 4) void attn_kernel(
    const _Float16* __restrict__ qh, const _Float16* __restrict__ kh,
    const _Float16* __restrict__ vth, _Float16* __restrict__ ctx) {
  __shared__ __align__(16) _Float16 Ks[2][2][64 * 64];   // [grp][buf] 32 KB
  __shared__ __align__(16) _Float16 Vs[2][2][64 * 64];   // [grp][buf] 32 KB

  const int tid = threadIdx.x, lane = tid & 63, wave = tid >> 6;
  const int sub = wave & 3, grp = wave >> 2;
  const int quad = lane >> 4, c16 = lane & 15;
  const int h = blockIdx.y;
  const int qw = blockIdx.x * 128 + sub * 32;

  // Q fragments (B-operand of 16x16x32)
  half8 qf[2][2];
#pragma unroll
  for (int qg = 0; qg < 2; ++qg)
#pragma unroll
    for (int c = 0; c < 2; ++c)
      qf[qg][c] = *(const half8*)(qh + (size_t)(h * T_SEQ + qw + qg * 16 + c16) * DH + c * 32 + quad * 8);

  // staging: within its group, wave 'sub' stages chunks {2sub,2sub+1} of K and V^T
  const int rs0 = sub * 16 + (lane >> 3);
  const int rs1 = rs0 + 8;
  const int dm0 = ((lane & 7) ^ (rs0 & 7)) * 8;
  const int dm1 = ((lane & 7) ^ (rs1 & 7)) * 8;
  const _Float16* gK0 = kh  + (size_t)(h * T_SEQ + grp * 2048 + rs0) * DH + dm0;
  const _Float16* gK1 = kh  + (size_t)(h * T_SEQ + grp * 2048 + rs1) * DH + dm1;
  const _Float16* gV0 = vth + (size_t)(h * DH + rs0) * T_SEQ + grp * 2048 + dm0;
  const _Float16* gV1 = vth + (size_t)(h * DH + rs1) * T_SEQ + grp * 2048 + dm1;
  const int lo0 = sub * 1024, lo1 = sub * 1024 + 512;

  f32x4 o[2][4];
  f32x4 lacc[2];
  const f32x4 zf = {0.f, 0.f, 0.f, 0.f};
#pragma unroll
  for (int qg = 0; qg < 2; ++qg) {
#pragma unroll
    for (int db = 0; db < 4; ++db) o[qg][db] = zf;
    lacc[qg] = zf;
  }
  const half8 ones8 = { (_Float16)1, (_Float16)1, (_Float16)1, (_Float16)1,
                        (_Float16)1, (_Float16)1, (_Float16)1, (_Float16)1 };

  auto stage = [&](int b) {
    gl_lds16(gK0, &Ks[grp][b][lo0]);
    gl_lds16(gK1, &Ks[grp][b][lo1]);
    gl_lds16(gV0, &Vs[grp][b][lo0]);
    gl_lds16(gV1, &Vs[grp][b][lo1]);
    gK0 += 64 * DH; gK1 += 64 * DH; gV0 += 64; gV1 += 64;
  };

  union U8 { uint32_t u[4]; half8 h; };

  auto compute = [&](int bc) {
    const _Float16* Kb = &Ks[grp][bc][0];
    const _Float16* Vb = &Vs[grp][bc][0];

    // S^T - 16: s[qg][kb][r] = score[key=kb*16+quad*4+r][qcol=qg*16+c16] - 16
    const f32x4 minit = {-16.f, -16.f, -16.f, -16.f};
    f32x4 s[2][4];
#pragma unroll
    for (int qg = 0; qg < 2; ++qg)
#pragma unroll
      for (int kb = 0; kb < 4; ++kb) s[qg][kb] = minit;
    __builtin_amdgcn_s_setprio(1);
#pragma unroll
    for (int c = 0; c < 2; ++c) {
#pragma unroll
      for (int kb = 0; kb < 4; ++kb) {
        int key = kb * 16 + c16;
        half8 ak = *(const half8*)(Kb + key * 64 + (((c * 4 + quad) ^ (key & 7)) * 8));
        s[0][kb] = MFMA_K32(ak, qf[0][c], s[0][kb]);
        s[1][kb] = MFMA_K32(ak, qf[1][c], s[1][kb]);
      }
    }
    __builtin_amdgcn_s_setprio(0);

    // p = exp2(s); build PV B-frags in registers (cvt_pkrtz + permlane swaps)
    half8 bp[2][2];   // [qg][kb32]
#pragma unroll
    for (int qg = 0; qg < 2; ++qg) {
      float p[4][4];
#pragma unroll
      for (int kb = 0; kb < 4; ++kb)
#pragma unroll
        for (int r = 0; r < 4; ++r) p[kb][r] = EXP2F(s[qg][kb][r]);
#pragma unroll
      for (int kb32 = 0; kb32 < 2; ++kb32) {
        uint32_t a0 = pk2(p[2 * kb32][0],     p[2 * kb32][1]);
        uint32_t a1 = pk2(p[2 * kb32][2],     p[2 * kb32][3]);
        uint32_t b0 = pk2(p[2 * kb32 + 1][0], p[2 * kb32 + 1][1]);
        uint32_t b1 = pk2(p[2 * kb32 + 1][2], p[2 * kb32 + 1][3]);
        asm("v_permlane32_swap_b32 %0, %1" : "+v"(a0), "+v"(b0));
        asm("v_permlane16_swap_b32 %0, %1" : "+v"(a0), "+v"(b0));
        asm("v_permlane32_swap_b32 %0, %1" : "+v"(a1), "+v"(b1));
        asm("v_permlane16_swap_b32 %0, %1" : "+v"(a1), "+v"(b1));
        U8 u;
        u.u[0] = a0; u.u[1] = a1; u.u[2] = b0; u.u[3] = b1;
        bp[qg][kb32] = u.h;
      }
    }

    // PV + l MFMA; V A-frags read per kb32 (conflict-free b128)
    __builtin_amdgcn_s_setprio(1);
#pragma unroll
    for (int kb32 = 0; kb32 < 2; ++kb32) {
      half8 av[4];
#pragma unroll
      for (int db = 0; db < 4; ++db) {
        int d = db * 16 + c16;
        av[db] = *(const half8*)(Vb + d * 64 + (((kb32 * 4 + quad) ^ (d & 7)) * 8));
      }
#pragma unroll
      for (int qg = 0; qg < 2; ++qg) {
        lacc[qg] = MFMA_K32(ones8, bp[qg][kb32], lacc[qg]);
#pragma unroll
        for (int db = 0; db < 4; ++db)
          o[qg][db] = MFMA_K32(av[db], bp[qg][kb32], o[qg][db]);
      }
    }
    __builtin_amdgcn_s_setprio(0);
  };

  // 32 tiles per group, double-buffered, one barrier per tile.
  stage(0);
  __syncthreads();
  for (int s = 0; s < 32; ++s) {
    if (s < 31) stage((s + 1) & 1);
    compute(s & 1);
    __syncthreads();
  }

  // ---- combine partials across groups via LDS ----
  float* oX = (float*)&Ks[0][0][0];                           // 32 KB
  float* lX = (float*)((char*)&Vs[0][0][0] + 16384);          // 2 KB (Vs[1] region)
  if (grp == 1) {
#pragma unroll
    for (int qg = 0; qg < 2; ++qg) {
#pragma unroll
      for (int db = 0; db < 4; ++db)
        *(f32x4*)(oX + (size_t)(((sub * 2 + qg) * 4 + db) * 64 + lane) * 4) = o[qg][db];
      lX[(sub * 2 + qg) * 64 + lane] = lacc[qg][0];
    }
  }
  __syncthreads();
  if (grp == 0) {
#pragma unroll
    for (int qg = 0; qg < 2; ++qg) {
#pragma unroll
      for (int db = 0; db < 4; ++db) {
        f32x4 ob = *(const f32x4*)(oX + (size_t)(((sub * 2 + qg) * 4 + db) * 64 + lane) * 4);
        o[qg][db] += ob;
      }
      lacc[qg][0] += lX[(sub * 2 + qg) * 64 + lane];
    }

    // epilogue: O/l -> per-sub LDS region (XOR swizzle) -> coalesced stores
    _Float16* Pw = &Vs[0][0][0] + sub * 2048;   // 4 KB per sub, Vs[0] region
#pragma unroll
    for (int qg = 0; qg < 2; ++qg) {
      float inv = 1.f / lacc[qg][0];
#pragma unroll
      for (int db = 0; db < 4; ++db) {
        half4 h4;
#pragma unroll
        for (int r = 0; r < 4; ++r) h4[r] = (_Float16)(o[qg][db][r] * inv);
        int row = qg * 16 + c16;
        int g   = db * 2 + (quad >> 1);
        *(half4*)(Pw + row * 64 + ((g ^ (row & 7)) * 8) + (quad & 1) * 4) = h4;
      }
    }
    const int q = lane >> 1, hv = lane & 1;
#pragma unroll
    for (int i = 0; i < 4; ++i) {
      int g = hv * 4 + i;
      half8 vv = *(const half8*)(Pw + q * 64 + ((g ^ (q & 7)) * 8));
      *(half8*)(ctx + (size_t)(qw + q) * CDIM + h * DH + g * 8) = vv;
    }
  }
}

// ---------------- launch ----------------
extern "C" void kernel_launch(void* const* d_in, const int* in_sizes, int n_in,
                              void* d_out, int out_size, void* d_ws, size_t ws_size,
                              hipStream_t stream) {
  const float* x  = (const float*)d_in[0];
  const float* Wq = (const float*)d_in[1];
  const float* bq = (const float*)d_in[2];
  const float* Wk = (const float*)d_in[3];
  const float* bk = (const float*)d_in[4];
  const float* Wv = (const float*)d_in[5];
  const float* bv = (const float*)d_in[6];
  const float* Wo = (const float*)d_in[7];
  const float* bo = (const float*)d_in[8];
  float* out = (float*)d_out;

  char* ws = (char*)d_ws;
  _Float16* xh  = (_Float16*)(ws);                    // 8 MB; reused as ctx after QKV
  _Float16* qh  = (_Float16*)(ws + ((size_t)8  << 20));
  _Float16* kh  = (_Float16*)(ws + ((size_t)16 << 20));
  _Float16* vth = (_Float16*)(ws + ((size_t)24 << 20));   // 8 MB [H][D][T]
  _Float16* wqh = (_Float16*)(ws + ((size_t)32 << 20));
  _Float16* wkh = (_Float16*)(ws + ((size_t)34 << 20));
  _Float16* wvh = (_Float16*)(ws + ((size_t)36 << 20));
  _Float16* woh = (_Float16*)(ws + ((size_t)38 << 20));
  _Float16* ctx = xh;  // xh dead after QKV GEMMs

  cvt_all_kernel<<<dim3(512, 8), 256, 0, stream>>>(Wq, Wk, Wv, Wo, x,
                                                   wqh, wkh, wvh, woh, xh);
  qkv_gemm<<<dim3(32, 8, 3), 256, 0, stream>>>(xh, wqh, wkh, wvh, bq, bk, bv, qh, kh, vth);
  attn_kernel<<<dim3(32, 16), 512, 0, stream>>>(qh, kh, vth, ctx);
  out_gemm<<<dim3(64, 8), 256, 0, stream>>>(ctx, woh, bo, out);
}

// Round 9
// 213.234 us; speedup vs baseline: 1.0868x; 1.0400x over previous
//
#include <hip/hip_runtime.h>
#include <stdint.h>

#define T_SEQ 4096
#define CDIM  1024
#define NH    16
#define DH    64

typedef _Float16 half8 __attribute__((ext_vector_type(8)));
typedef _Float16 half4 __attribute__((ext_vector_type(4)));
typedef float    f32x4 __attribute__((ext_vector_type(4)));

#if __has_builtin(__builtin_amdgcn_exp2f)
#define EXP2F(x) __builtin_amdgcn_exp2f(x)
#else
#define EXP2F(x) exp2f(x)
#endif

#define MFMA_K32(a, b, c) __builtin_amdgcn_mfma_f32_16x16x32_f16(a, b, c, 0, 0, 0)

// pack 2 f32 -> dword of 2 f16 (RTZ): low = a, high = b
__device__ __forceinline__ uint32_t pk2(float a, float b) {
  auto h = __builtin_amdgcn_cvt_pkrtz(a, b);   // __fp16 ext_vector(2)
  return __builtin_bit_cast(uint32_t, h);
}

// async global->LDS, 16B per lane. LDS dest = wave-uniform base + lane*16.
__device__ __forceinline__ void gl_lds16(const void* g, void* l) {
  __builtin_amdgcn_global_load_lds(
      (const __attribute__((address_space(1))) uint32_t*)g,
      (__attribute__((address_space(3))) uint32_t*)l, 16, 0, 0);
}

// ---------------- fp32 -> fp16 convert (weights y=0..3, x y=4..7) ----------------
__global__ void cvt_all_kernel(const float* __restrict__ w0, const float* __restrict__ w1,
                               const float* __restrict__ w2, const float* __restrict__ w3,
                               const float* __restrict__ x,
                               _Float16* __restrict__ o0, _Float16* __restrict__ o1,
                               _Float16* __restrict__ o2, _Float16* __restrict__ o3,
                               _Float16* __restrict__ xo) {
  int y = blockIdx.y;
  const float* src;
  _Float16* dst;
  if (y < 4) {
    src = (y == 0) ? w0 : (y == 1) ? w1 : (y == 2) ? w2 : w3;
    dst = (y == 0) ? o0 : (y == 1) ? o1 : (y == 2) ? o2 : o3;
  } else {
    src = x  + (size_t)(y - 4) * (CDIM * CDIM);
    dst = xo + (size_t)(y - 4) * (CDIM * CDIM);
  }
  int i = (blockIdx.x * blockDim.x + threadIdx.x) * 8;
  float4 f0 = *(const float4*)(src + i);
  float4 f1 = *(const float4*)(src + i + 4);
  half8 h = { (_Float16)f0.x, (_Float16)f0.y, (_Float16)f0.z, (_Float16)f0.w,
              (_Float16)f1.x, (_Float16)f1.y, (_Float16)f1.z, (_Float16)f1.w };
  *(half8*)(dst + i) = h;
}

// ---------------- GEMM core 128x128: C += A[128xK] * B[128xK]^T ----------------
__device__ __forceinline__ void gemm_core(const _Float16* __restrict__ A,
                                          const _Float16* __restrict__ Bm,
                                          _Float16* As, _Float16* Bs,
                                          int bm, int bn,
                                          f32x4 (&acc)[4][4]) {
  const int tid  = threadIdx.x;
  const int lane = tid & 63;
  const int wave = tid >> 6;
  const int waveM = wave >> 1, waveN = wave & 1;
  const int quad = lane >> 4, c16 = lane & 15;

  const int rs0 = wave * 32 + (lane >> 2);
  const int rs1 = rs0 + 16;
  const int dm0 = ((lane & 3) ^ ((rs0 >> 1) & 3)) * 8;
  const int dm1 = ((lane & 3) ^ ((rs1 >> 1) & 3)) * 8;

  const _Float16* gA0 = A  + (size_t)(bm * 128 + rs0) * CDIM + dm0;
  const _Float16* gA1 = A  + (size_t)(bm * 128 + rs1) * CDIM + dm1;
  const _Float16* gB0 = Bm + (size_t)(bn * 128 + rs0) * CDIM + dm0;
  const _Float16* gB1 = Bm + (size_t)(bn * 128 + rs1) * CDIM + dm1;
  _Float16* lA0 = As + wave * 1024;
  _Float16* lA1 = lA0 + 512;
  _Float16* lB0 = Bs + wave * 1024;
  _Float16* lB1 = lB0 + 512;

  const int xsw  = (c16 >> 1) & 3;
  const int offA = (waveM * 64 + c16) * 32 + ((quad ^ xsw) * 8);
  const int offB = (waveN * 64 + c16) * 32 + ((quad ^ xsw) * 8);

  for (int kk = 0; kk < 32; ++kk) {
    gl_lds16(gA0, lA0);
    gl_lds16(gA1, lA1);
    gl_lds16(gB0, lB0);
    gl_lds16(gB1, lB1);
    __syncthreads();
    half8 a[4], b[4];
#pragma unroll
    for (int i = 0; i < 4; ++i) a[i] = *(const half8*)(As + offA + i * 512);
#pragma unroll
    for (int i = 0; i < 4; ++i) b[i] = *(const half8*)(Bs + offB + i * 512);
#pragma unroll
    for (int mi = 0; mi < 4; ++mi)
#pragma unroll
      for (int ni = 0; ni < 4; ++ni)
        acc[mi][ni] = MFMA_K32(a[mi], b[ni], acc[mi][ni]);
    gA0 += 32; gA1 += 32; gB0 += 32; gB1 += 32;
    __syncthreads();
  }
}

// ---------------- GEMM core 64x128: C += A[64xK] * B[128xK]^T ----------------
__device__ __forceinline__ void gemm_core64(const _Float16* __restrict__ A,
                                            const _Float16* __restrict__ Bm,
                                            _Float16* As, _Float16* Bs,
                                            int bm, int bn,
                                            f32x4 (&acc)[2][4]) {
  const int tid  = threadIdx.x;
  const int lane = tid & 63;
  const int wave = tid >> 6;
  const int waveM = wave >> 1, waveN = wave & 1;
  const int quad = lane >> 4, c16 = lane & 15;

  const int rsA = wave * 16 + (lane >> 2);
  const int dmA = ((lane & 3) ^ ((rsA >> 1) & 3)) * 8;
  const int rs0 = wave * 32 + (lane >> 2);
  const int rs1 = rs0 + 16;
  const int dm0 = ((lane & 3) ^ ((rs0 >> 1) & 3)) * 8;
  const int dm1 = ((lane & 3) ^ ((rs1 >> 1) & 3)) * 8;

  const _Float16* gA0 = A  + (size_t)(bm * 64  + rsA) * CDIM + dmA;
  const _Float16* gB0 = Bm + (size_t)(bn * 128 + rs0) * CDIM + dm0;
  const _Float16* gB1 = Bm + (size_t)(bn * 128 + rs1) * CDIM + dm1;
  _Float16* lA0 = As + wave * 512;
  _Float16* lB0 = Bs + wave * 1024;
  _Float16* lB1 = lB0 + 512;

  const int xsw  = (c16 >> 1) & 3;
  const int offA = (waveM * 32 + c16) * 32 + ((quad ^ xsw) * 8);
  const int offB = (waveN * 64 + c16) * 32 + ((quad ^ xsw) * 8);

  for (int kk = 0; kk < 32; ++kk) {
    gl_lds16(gA0, lA0);
    gl_lds16(gB0, lB0);
    gl_lds16(gB1, lB1);
    __syncthreads();
    half8 a[2], b[4];
#pragma unroll
    for (int i = 0; i < 2; ++i) a[i] = *(const half8*)(As + offA + i * 512);
#pragma unroll
    for (int i = 0; i < 4; ++i) b[i] = *(const half8*)(Bs + offB + i * 512);
#pragma unroll
    for (int mi = 0; mi < 2; ++mi)
#pragma unroll
      for (int ni = 0; ni < 4; ++ni)
        acc[mi][ni] = MFMA_K32(a[mi], b[ni], acc[mi][ni]);
    gA0 += 32; gB0 += 32; gB1 += 32;
    __syncthreads();
  }
}

// ---------------- fused QKV projection ----------------
// z=0: q -> qh [H][T][D] scaled by (1/8)*log2(e); z=1: k -> kh [H][T][D];
// z=2: v -> vth [H][D][T] (V^T; attn stages it to LDS and reads half8 A-frags).
__global__ __launch_bounds__(256) void qkv_gemm(
    const _Float16* __restrict__ xh,
    const _Float16* __restrict__ wqh, const _Float16* __restrict__ wkh, const _Float16* __restrict__ wvh,
    const float* __restrict__ bq, const float* __restrict__ bk, const float* __restrict__ bv,
    _Float16* __restrict__ qh, _Float16* __restrict__ kh, _Float16* __restrict__ vth) {
  __shared__ __align__(16) _Float16 As[128 * 32];
  __shared__ __align__(16) _Float16 Bs[128 * 32];
  const int z = blockIdx.z;
  const _Float16* W   = (z == 0) ? wqh : ((z == 1) ? wkh : wvh);
  const float*    bias = (z == 0) ? bq  : ((z == 1) ? bk  : bv);

  f32x4 acc[4][4];
  const f32x4 zf = {0.f, 0.f, 0.f, 0.f};
#pragma unroll
  for (int i = 0; i < 4; ++i)
#pragma unroll
    for (int j = 0; j < 4; ++j) acc[i][j] = zf;

  gemm_core(xh, W, As, Bs, blockIdx.x, blockIdx.y, acc);

  const int lane = threadIdx.x & 63, wave = threadIdx.x >> 6;
  const int waveM = wave >> 1, waveN = wave & 1;
  const int quad = lane >> 4, c16 = lane & 15;
  const int rowb = blockIdx.x * 128 + waveM * 64;
  const int colb = blockIdx.y * 128 + waveN * 64;

  float bsv[4];
#pragma unroll
  for (int ni = 0; ni < 4; ++ni) bsv[ni] = bias[colb + ni * 16 + c16];

  if (z < 2) {
    _Float16* outp = (z == 0) ? qh : kh;
    const float scl = (z == 0) ? 0.18033688011112042f : 1.0f;  // (1/8)*log2(e) folded into q
#pragma unroll
    for (int mi = 0; mi < 4; ++mi)
#pragma unroll
      for (int ni = 0; ni < 4; ++ni) {
        int col = colb + ni * 16 + c16;
        int hh = col >> 6, dd = col & 63;
#pragma unroll
        for (int r = 0; r < 4; ++r) {
          int row = rowb + mi * 16 + quad * 4 + r;
          outp[(size_t)(hh * T_SEQ + row) * DH + dd] = (_Float16)((acc[mi][ni][r] + bsv[ni]) * scl);
        }
      }
  } else {
#pragma unroll
    for (int mi = 0; mi < 4; ++mi)
#pragma unroll
      for (int ni = 0; ni < 4; ++ni) {
        int col  = colb + ni * 16 + c16;
        int row0 = rowb + mi * 16 + quad * 4;
        half4 h4;
#pragma unroll
        for (int r = 0; r < 4; ++r) h4[r] = (_Float16)(acc[mi][ni][r] + bsv[ni]);
        *(half4*)(vth + (size_t)col * T_SEQ + row0) = h4;   // [H][D][T]
      }
  }
}

// ---------------- output projection: out = ctx @ Wo^T + bo (fp32), 64x128 tiles ----------------
__global__ __launch_bounds__(256) void out_gemm(
    const _Float16* __restrict__ ctx, const _Float16* __restrict__ woh,
    const float* __restrict__ bo, float* __restrict__ out) {
  __shared__ __align__(16) _Float16 As[64 * 32];
  __shared__ __align__(16) _Float16 Bs[128 * 32];
  f32x4 acc[2][4];
  const f32x4 zf = {0.f, 0.f, 0.f, 0.f};
#pragma unroll
  for (int i = 0; i < 2; ++i)
#pragma unroll
    for (int j = 0; j < 4; ++j) acc[i][j] = zf;

  gemm_core64(ctx, woh, As, Bs, blockIdx.x, blockIdx.y, acc);

  const int lane = threadIdx.x & 63, wave = threadIdx.x >> 6;
  const int waveM = wave >> 1, waveN = wave & 1;
  const int quad = lane >> 4, c16 = lane & 15;
  const int rowb = blockIdx.x * 64 + waveM * 32;
  const int colb = blockIdx.y * 128 + waveN * 64;

  float bsv[4];
#pragma unroll
  for (int ni = 0; ni < 4; ++ni) bsv[ni] = bo[colb + ni * 16 + c16];

#pragma unroll
  for (int mi = 0; mi < 2; ++mi)
#pragma unroll
    for (int ni = 0; ni < 4; ++ni) {
      int col = colb + ni * 16 + c16;
#pragma unroll
      for (int r = 0; r < 4; ++r) {
        int row = rowb + mi * 16 + quad * 4 + r;
        out[(size_t)row * CDIM + col] = acc[mi][ni][r] + bsv[ni];
      }
    }
}

// ---------------- flash attention (R12: R7b verbatim + XCD-aware block swizzle) ----------------
// R10/R11 post-mortem: both dual-s-set reorders failed correctness (one
// intermittent, one NaN) while R7b's per-tile order passes -> the reorder
// line is abandoned (can't race-screen headlessly). R12 = R7b's proven
// structure byte-for-byte, plus ONE safe delta: XCD-aware block swizzle.
// Default l=y*32+x round-robins across 8 XCDs -> each head's 32 blocks span
// all XCDs, each XCD L2 fetches that head's K/V => FETCH 69.7MB vs ~17MB
// ideal. Remap (bijective, 512%8==0): c=l&7, i=l>>3, w=c*64+i -> XCD c
// handles heads {2c,2c+1} only; K/V per head cached on one XCD.
__global__ __launch_bounds__(256, 2) void attn_kernel(
    const _Float16* __restrict__ qh, const _Float16* __restrict__ kh,
    const _Float16* __restrict__ vth, _Float16* __restrict__ ctx) {
  __shared__ __align__(16) _Float16 Ks[4][64 * 64];   // 32 KB ring
  __shared__ __align__(16) _Float16 Vs[4][64 * 64];   // 32 KB ring

  const int tid = threadIdx.x, lane = tid & 63, wave = tid >> 6;
  const int quad = lane >> 4, c16 = lane & 15;
  // XCD-aware swizzle: hardware XCD ~ dispatch_index % 8; give XCD c heads {2c,2c+1}
  const int l  = blockIdx.y * 32 + blockIdx.x;
  const int w  = (l & 7) * 64 + (l >> 3);
  const int h  = w >> 5;
  const int qw = (w & 31) * 128 + wave * 32;

  // Q fragments (B-operand of 16x16x32)
  half8 qf[2][2];
#pragma unroll
  for (int qg = 0; qg < 2; ++qg)
#pragma unroll
    for (int c = 0; c < 2; ++c)
      qf[qg][c] = *(const half8*)(qh + (size_t)(h * T_SEQ + qw + qg * 16 + c16) * DH + c * 32 + quad * 8);

  // staging: wave w stages chunks {2w,2w+1} (8 rows x 128B) of K and V^T
  const int rs0 = wave * 16 + (lane >> 3);
  const int rs1 = rs0 + 8;
  const int dm0 = ((lane & 7) ^ (rs0 & 7)) * 8;
  const int dm1 = ((lane & 7) ^ (rs1 & 7)) * 8;
  const _Float16* gK0 = kh  + (size_t)(h * T_SEQ + rs0) * DH + dm0;
  const _Float16* gK1 = kh  + (size_t)(h * T_SEQ + rs1) * DH + dm1;
  const _Float16* gV0 = vth + (size_t)(h * DH + rs0) * T_SEQ + dm0;
  const _Float16* gV1 = vth + (size_t)(h * DH + rs1) * T_SEQ + dm1;
  const int lo0 = wave * 1024, lo1 = wave * 1024 + 512;

  f32x4 o[2][4];
  f32x4 lacc[2];
  const f32x4 zf = {0.f, 0.f, 0.f, 0.f};
#pragma unroll
  for (int qg = 0; qg < 2; ++qg) {
#pragma unroll
    for (int db = 0; db < 4; ++db) o[qg][db] = zf;
    lacc[qg] = zf;
  }
  const half8 ones8 = { (_Float16)1, (_Float16)1, (_Float16)1, (_Float16)1,
                        (_Float16)1, (_Float16)1, (_Float16)1, (_Float16)1 };

  // stage one 64-key tile of K and V^T into ring buffer b; advance pointers
  auto stage = [&](int b) {
    gl_lds16(gK0, &Ks[b][lo0]);
    gl_lds16(gK1, &Ks[b][lo1]);
    gl_lds16(gV0, &Vs[b][lo0]);
    gl_lds16(gV1, &Vs[b][lo1]);
    gK0 += 64 * DH; gK1 += 64 * DH; gV0 += 64; gV1 += 64;
  };

  union U8 { uint32_t u[4]; half8 h; };

  auto compute = [&](int bc) {
    const _Float16* Kb = &Ks[bc][0];
    const _Float16* Vb = &Vs[bc][0];

    // S^T - 16: s[qg][kb][r] = score[key=kb*16+quad*4+r][qcol=qg*16+c16] - 16
    const f32x4 minit = {-16.f, -16.f, -16.f, -16.f};
    f32x4 s[2][4];
#pragma unroll
    for (int qg = 0; qg < 2; ++qg)
#pragma unroll
      for (int kb = 0; kb < 4; ++kb) s[qg][kb] = minit;
    __builtin_amdgcn_s_setprio(1);
#pragma unroll
    for (int c = 0; c < 2; ++c) {
#pragma unroll
      for (int kb = 0; kb < 4; ++kb) {
        int key = kb * 16 + c16;
        half8 ak = *(const half8*)(Kb + key * 64 + (((c * 4 + quad) ^ (key & 7)) * 8));
        s[0][kb] = MFMA_K32(ak, qf[0][c], s[0][kb]);
        s[1][kb] = MFMA_K32(ak, qf[1][c], s[1][kb]);
      }
    }
    __builtin_amdgcn_s_setprio(0);

    // p = exp2(s); build PV B-frags fully in registers (no LDS round-trip)
    half8 bp[2][2];   // [qg][kb32]
#pragma unroll
    for (int qg = 0; qg < 2; ++qg) {
      float p[4][4];
#pragma unroll
      for (int kb = 0; kb < 4; ++kb)
#pragma unroll
        for (int r = 0; r < 4; ++r) p[kb][r] = EXP2F(s[qg][kb][r]);
#pragma unroll
      for (int kb32 = 0; kb32 < 2; ++kb32) {
        uint32_t a0 = pk2(p[2 * kb32][0],     p[2 * kb32][1]);
        uint32_t a1 = pk2(p[2 * kb32][2],     p[2 * kb32][3]);
        uint32_t b0 = pk2(p[2 * kb32 + 1][0], p[2 * kb32 + 1][1]);
        uint32_t b1 = pk2(p[2 * kb32 + 1][2], p[2 * kb32 + 1][3]);
        asm("v_permlane32_swap_b32 %0, %1" : "+v"(a0), "+v"(b0));
        asm("v_permlane16_swap_b32 %0, %1" : "+v"(a0), "+v"(b0));
        asm("v_permlane32_swap_b32 %0, %1" : "+v"(a1), "+v"(b1));
        asm("v_permlane16_swap_b32 %0, %1" : "+v"(a1), "+v"(b1));
        U8 u;
        u.u[0] = a0; u.u[1] = a1; u.u[2] = b0; u.u[3] = b1;
        bp[qg][kb32] = u.h;
      }
    }

    // PV + l MFMA; V A-frags read per kb32 (conflict-free b128)
    __builtin_amdgcn_s_setprio(1);
#pragma unroll
    for (int kb32 = 0; kb32 < 2; ++kb32) {
      half8 av[4];
#pragma unroll
      for (int db = 0; db < 4; ++db) {
        int d = db * 16 + c16;
        av[db] = *(const half8*)(Vb + d * 64 + (((kb32 * 4 + quad) ^ (d & 7)) * 8));
      }
#pragma unroll
      for (int qg = 0; qg < 2; ++qg) {
        lacc[qg] = MFMA_K32(ones8, bp[qg][kb32], lacc[qg]);
#pragma unroll
        for (int db = 0; db < 4; ++db)
          o[qg][db] = MFMA_K32(av[db], bp[qg][kb32], o[qg][db]);
      }
    }
    __builtin_amdgcn_s_setprio(0);
  };

  // prologue: tiles 0,1 into bufs 0,1
  stage(0);
  stage(1);
  __syncthreads();

  // 64 tiles, ring-4, one barrier per 2 tiles. Iter jj: computes 4jj..4jj+3.
  for (int jj = 0; jj < 16; ++jj) {
    stage(2); stage(3);          // tiles 4jj+2, 4jj+3
    compute(0); compute(1);      // tiles 4jj,   4jj+1
    __syncthreads();
    if (jj < 15) { stage(0); stage(1); }   // tiles 4jj+4, 4jj+5
    compute(2); compute(3);      // tiles 4jj+2, 4jj+3
    __syncthreads();
  }

  // epilogue: O/l -> wave-private LDS (reuse Ks; 4KB/wave) -> coalesced stores
  _Float16* Pw = &Ks[0][0] + wave * 2048;
#pragma unroll
  for (int qg = 0; qg < 2; ++qg) {
    float inv = 1.f / lacc[qg][0];   // every reg of lacc holds l[q=c16]
#pragma unroll
    for (int db = 0; db < 4; ++db) {
      half4 h4;
#pragma unroll
      for (int r = 0; r < 4; ++r) h4[r] = (_Float16)(o[qg][db][r] * inv);
      int row = qg * 16 + c16;
      int g   = db * 2 + (quad >> 1);
      *(half4*)(Pw + row * 64 + ((g ^ (row & 7)) * 8) + (quad & 1) * 4) = h4;
    }
  }
  const int q = lane >> 1, hv = lane & 1;
#pragma unroll
  for (int i = 0; i < 4; ++i) {
    int g = hv * 4 + i;
    half8 vv = *(const half8*)(Pw + q * 64 + ((g ^ (q & 7)) * 8));
    *(half8*)(ctx + (size_t)(qw + q) * CDIM + h * DH + g * 8) = vv;
  }
}

// ---------------- launch ----------------
extern "C" void kernel_launch(void* const* d_in, const int* in_sizes, int n_in,
                              void* d_out, int out_size, void* d_ws, size_t ws_size,
                              hipStream_t stream) {
  const float* x  = (const float*)d_in[0];
  const float* Wq = (const float*)d_in[1];
  const float* bq = (const float*)d_in[2];
  const float* Wk = (const float*)d_in[3];
  const float* bk = (const float*)d_in[4];
  const float* Wv = (const float*)d_in[5];
  const float* bv = (const float*)d_in[6];
  const float* Wo = (const float*)d_in[7];
  const float* bo = (const float*)d_in[8];
  float* out = (float*)d_out;

  char* ws = (char*)d_ws;
  _Float16* xh  = (_Float16*)(ws);                    // 8 MB; reused as ctx after QKV
  _Float16* qh  = (_Float16*)(ws + ((size_t)8  << 20));
  _Float16* kh  = (_Float16*)(ws + ((size_t)16 << 20));
  _Float16* vth = (_Float16*)(ws + ((size_t)24 << 20));   // 8 MB [H][D][T]
  _Float16* wqh = (_Float16*)(ws + ((size_t)32 << 20));
  _Float16* wkh = (_Float16*)(ws + ((size_t)34 << 20));
  _Float16* wvh = (_Float16*)(ws + ((size_t)36 << 20));
  _Float16* woh = (_Float16*)(ws + ((size_t)38 << 20));
  _Float16* ctx = xh;  // xh dead after QKV GEMMs

  cvt_all_kernel<<<dim3(512, 8), 256, 0, stream>>>(Wq, Wk, Wv, Wo, x,
                                                   wqh, wkh, wvh, woh, xh);
  qkv_gemm<<<dim3(32, 8, 3), 256, 0, stream>>>(xh, wqh, wkh, wvh, bq, bk, bv, qh, kh, vth);
  attn_kernel<<<dim3(32, 16), 256, 0, stream>>>(qh, kh, vth, ctx);
  out_gemm<<<dim3(64, 8), 256, 0, stream>>>(ctx, woh, bo, out);
}